// Round 5
// baseline (14003.316 us; speedup 1.0000x reference)
//
#include <hip/hip_runtime.h>

#define B_ 128
#define T_ 256
#define F_ 128
#define H_ 768
#define NG 3072
#define BH (B_*H_)
#define RD 8             // h ring depth

typedef short s16x8 __attribute__((ext_vector_type(8)));
typedef float f32x4 __attribute__((ext_vector_type(4)));
typedef unsigned short ushort_t;

__device__ __forceinline__ unsigned short f2bf(float x) {
  unsigned u = __float_as_uint(x);
  u += 0x7fffu + ((u >> 16) & 1u);
  return (unsigned short)(u >> 16);
}

__device__ __forceinline__ void async16(const void* g, void* l) {
  __builtin_amdgcn_global_load_lds(
      (const __attribute__((address_space(1))) void*)g,
      (__attribute__((address_space(3))) void*)l, 16, 0, 0);
}

// flags: [0]=abort; fh0[514*96]; fh1[514*96]; yd[514*4]  (one word per value+panel; no reuse)
#define NSLOT 514
#define FH_SZ (NSLOT*96)
#define YD_SZ (NSLOT*4)
#define FL_TOTAL (1 + 2*FH_SZ + YD_SZ)

struct PR {
  const ushort_t* xbf;
  const char *WAenc, *WBenc, *WAdec, *WBdec, *WY;      // packed LDS images
  const float *bAenc, *bBenc, *bAdec, *bBdec;          // [96][32] permuted biases
  const float* g0p;                                    // [128][3072] packed x-gates for cd0(0)
  const float* linb;
  ushort_t *h0ring, *h1ring;
  float *c0, *c1;
  int* flags;
  float* out;
};

// 96(or 4)-thread parallel spin: thread i watches flags[i]; single barrier joins.
__device__ bool waitN(int* fl, int count, int* abortf, int* sres, int tid) {
  if (tid == 0) *sres = 1;
  __syncthreads();
  bool ok = true;
  if (tid < count) {
    if (__hip_atomic_load(fl + tid, __ATOMIC_RELAXED, __HIP_MEMORY_SCOPE_AGENT) == 0) {
      long n = 0;
      for (;;) {
        if (__hip_atomic_load(fl + tid, __ATOMIC_RELAXED, __HIP_MEMORY_SCOPE_AGENT) != 0) break;
        __builtin_amdgcn_s_sleep(1);
        if ((++n & 63) == 0) {
          if (__hip_atomic_load(abortf, __ATOMIC_RELAXED, __HIP_MEMORY_SCOPE_AGENT)) { ok = false; break; }
          if (n > 1500000) {
            __hip_atomic_store(abortf, 1, __ATOMIC_RELAXED, __HIP_MEMORY_SCOPE_AGENT);
            ok = false; break;
          }
        }
      }
    }
    if (ok) (void)__hip_atomic_load(fl + tid, __ATOMIC_ACQUIRE, __HIP_MEMORY_SCOPE_AGENT);
  }
  if (!ok) *sres = 0;
  __syncthreads();
  return *sres != 0;
}

__device__ __forceinline__ void postf(int* fl) {
  __hip_atomic_store(fl, 1, __ATOMIC_RELEASE, __HIP_MEMORY_SCOPE_AGENT);
}

__device__ __forceinline__ void loadW(char* ldsW, const char* src, int bytes, int wave, int lane) {
  __syncthreads();
  for (int cb = wave * 1024; cb < bytes; cb += 4096)
    async16(src + cb + lane * 16, ldsW + cb);
  __syncthreads();                          // vmcnt(0) drain + barrier
}

// stage one 64-K chunk of the M=128 A-operand: exactly 4 global_load_lds per wave
__device__ __forceinline__ void stageA(char* dst, const ushort_t* aptr, long lda,
                                       int kk, int wave, int lane) {
#pragma unroll
  for (int q = 0; q < 4; ++q) {
    int cb = (q * 4 + wave) * 1024;
    int P = cb + lane * 16;
    int r = P >> 7;                         // row 0..127 (128B rows)
    int sl = ((P >> 4) & 7) ^ (r & 7);      // XOR-swizzled 16B slot
    const ushort_t* gp = aptr + (long)r * lda + kk + sl * 8;
    async16(gp, dst + cb);
  }
}

__device__ __forceinline__ void comp_slab(const char* At, const char* Wt, int rowBytes,
                                          int slotbase, f32x4 acc[2][2], int wave, int lane) {
#pragma unroll
  for (int ks = 0; ks < 2; ++ks) {
    s16x8 a[2], bb[2];
#pragma unroll
    for (int mf = 0; mf < 2; ++mf) {
      int r = wave * 32 + mf * 16 + (lane & 15);
      int sl = (ks * 4 + (lane >> 4)) ^ (r & 7);
      a[mf] = *(const s16x8*)(At + r * 128 + sl * 16);
    }
#pragma unroll
    for (int nf = 0; nf < 2; ++nf) {
      int c = nf * 16 + (lane & 15);
      int sl = (slotbase + ks * 4 + (lane >> 4)) ^ (c & 7);
      bb[nf] = *(const s16x8*)(Wt + (long)c * rowBytes + sl * 16);
    }
#pragma unroll
    for (int mf = 0; mf < 2; ++mf)
#pragma unroll
      for (int nf = 0; nf < 2; ++nf)
        acc[mf][nf] = __builtin_amdgcn_mfma_f32_16x16x32_bf16(a[mf], bb[nf], acc[mf][nf], 0, 0, 0);
  }
}

// counted-vmcnt 3-ring K-loop: vmcnt(4) keeps one newer chunk in flight (round-4 proven)
__device__ void run_seg(const char* ldsW, char (*ldsA)[16384], const ushort_t* aptr,
                        long lda, int slot0, int nslab, int rowBytes, f32x4 acc[2][2],
                        int wave, int lane) {
  __syncthreads();                          // prior LDS-A uses complete
  stageA(ldsA[0], aptr, lda, 0, wave, lane);
  if (nslab > 1) stageA(ldsA[1], aptr, lda, 64, wave, lane);
  for (int it = 0; it < nslab; ++it) {
    if (it + 1 < nslab) asm volatile("s_waitcnt vmcnt(4)" ::: "memory");
    else                asm volatile("s_waitcnt vmcnt(0)" ::: "memory");
    __builtin_amdgcn_s_barrier();
    __builtin_amdgcn_sched_barrier(0);
    if (it + 2 < nslab) stageA(ldsA[(it + 2) % 3], aptr, lda, (it + 2) * 64, wave, lane);
    comp_slab(ldsA[it % 3], ldsW, rowBytes, slot0 + it * 8, acc, wave, lane);
  }
}

__device__ void epi_gates(f32x4 acc[2][2], const float* bias32, const float* g0p,
                          float* cst, ushort_t* hdst, int tn, int wave, int lane) {
  int c0 = lane & 15, u = c0 & 7;
  bool act = c0 < 8;
  float bi = 0, bf_ = 0, bg = 0, bo = 0;
  if (!g0p) { bi = bias32[u]; bf_ = bias32[8 + u]; bg = bias32[16 + u]; bo = bias32[24 + u]; }
#pragma unroll
  for (int mf = 0; mf < 2; ++mf) {
    f32x4 fv, ov;
#pragma unroll
    for (int k = 0; k < 4; ++k) {
      fv[k] = __shfl_xor(acc[mf][0][k], 8);
      ov[k] = __shfl_xor(acc[mf][1][k], 8);
    }
    if (act) {
#pragma unroll
      for (int rg = 0; rg < 4; ++rg) {
        int r = wave * 32 + mf * 16 + ((lane >> 4) << 2) + rg;
        float gi = acc[mf][0][rg], gf = fv[rg], gg = acc[mf][1][rg], go = ov[rg];
        if (g0p) {
          const float* gr = g0p + (long)r * NG + tn * 32;
          gi += gr[u]; gf += gr[8 + u]; gg += gr[16 + u]; go += gr[24 + u];
        } else { gi += bi; gf += bf_; gg += bg; go += bo; }
        float iv = 1.f / (1.f + __expf(-gi));
        float fvv = 1.f / (1.f + __expf(-gf));
        float gc = fminf(fmaxf(gg, -15.f), 15.f);
        float eg = __expf(2.f * gc);
        float gv = (eg - 1.f) / (eg + 1.f);
        float ovv = 1.f / (1.f + __expf(-go));
        long ci = (long)r * H_ + tn * 8 + u;
        float c2 = fvv * cst[ci] + iv * gv;
        cst[ci] = c2;
        float cc = fminf(fmaxf(c2, -15.f), 15.f);
        float ec = __expf(2.f * cc);
        hdst[ci] = f2bf(ovv * ((ec - 1.f) / (ec + 1.f)));
      }
    }
  }
}

__global__ __launch_bounds__(256, 1) void lstm_res(PR p) {
  __shared__ char ldsW[98304];
  __shared__ char ldsA[3][16384];
  __shared__ int sres;
  const int b = blockIdx.x, tid = threadIdx.x;
  const int wave = tid >> 6, lane = tid & 63;
  int* abortf = p.flags;
  int* fh0 = p.flags + 1;
  int* fh1 = fh0 + FH_SZ;
  int* yd  = fh1 + FH_SZ;
  auto hs0 = [&](int v) { return p.h0ring + (size_t)(v & (RD - 1)) * BH; };
  auto hs1 = [&](int v) { return p.h1ring + (size_t)(v & (RD - 1)) * BH; };

  if (b < 96) {                             // ===== role A: enc0 -> cd0 =====
    const int tn = b;
    loadW(ldsW, p.WAenc + (size_t)tn * 57344, 57344, wave, lane);
    for (int t = 0; t < 256; ++t) {
      f32x4 acc[2][2] = {{{0,0,0,0},{0,0,0,0}},{{0,0,0,0},{0,0,0,0}}};
      run_seg(ldsW, ldsA, p.xbf + (long)t * F_, (long)T_ * F_, 0, 2, 1792, acc, wave, lane);
      if (t > 0 && !waitN(fh0 + t * 96, 96, abortf, &sres, tid)) return;
      run_seg(ldsW, ldsA, hs0(t), H_, 16, 12, 1792, acc, wave, lane);
      // ring guard: h0(t+1) overwrites h0(t-7); its reader enc1(t-8) is done once h1(t-7) exists
      if (t >= 8 && !waitN(fh1 + (t - 7) * 96, 96, abortf, &sres, tid)) return;
      epi_gates(acc, p.bAenc + tn * 32, nullptr, p.c0, hs0(t + 1), tn, wave, lane);
      __syncthreads();
      if (tid == 0) postf(fh0 + (t + 1) * 96 + tn);
    }
    loadW(ldsW, p.WAdec + (size_t)tn * 98304, 98304, wave, lane);
    {                                       // cd0(0): Whh0 half + g0 per-elem bias
      f32x4 acc[2][2] = {{{0,0,0,0},{0,0,0,0}},{{0,0,0,0},{0,0,0,0}}};
      if (!waitN(fh0 + 256 * 96, 96, abortf, &sres, tid)) return;
      run_seg(ldsW, ldsA, hs0(256), H_, 96, 12, 3072, acc, wave, lane);
      // ring guard: h0(257) overwrites h0(249); reader enc1(248) done once h1(249) exists
      if (!waitN(fh1 + 249 * 96, 96, abortf, &sres, tid)) return;
      epi_gates(acc, nullptr, p.g0p, p.c0, hs0(257), tn, wave, lane);
      __syncthreads();
      if (tid == 0) postf(fh0 + 257 * 96 + tn);
    }
    for (int t = 1; t < 256; ++t) {
      f32x4 acc[2][2] = {{{0,0,0,0},{0,0,0,0}},{{0,0,0,0},{0,0,0,0}}};
      if (!waitN(fh0 + (256 + t) * 96, 96, abortf, &sres, tid)) return;
      run_seg(ldsW, ldsA, hs0(256 + t), H_, 96, 12, 3072, acc, wave, lane);   // stale: Whh0
      if (!waitN(fh1 + (256 + t) * 96, 96, abortf, &sres, tid)) return;
      run_seg(ldsW, ldsA, hs1(256 + t), H_, 0, 12, 3072, acc, wave, lane);    // fresh: W_comb
      epi_gates(acc, p.bAdec + tn * 32, nullptr, p.c0, hs0(257 + t), tn, wave, lane);
      __syncthreads();
      if (tid == 0) postf(fh0 + (257 + t) * 96 + tn);
    }
  } else if (b < 192) {                     // ===== role B: enc1 -> cd1 =====
    const int tn = b - 96;
    loadW(ldsW, p.WBenc + (size_t)tn * 98304, 98304, wave, lane);
    for (int t = 0; t < 256; ++t) {
      f32x4 acc[2][2] = {{{0,0,0,0},{0,0,0,0}},{{0,0,0,0},{0,0,0,0}}};
      if (t > 0 && !waitN(fh1 + t * 96, 96, abortf, &sres, tid)) return;
      run_seg(ldsW, ldsA, hs1(t), H_, 96, 12, 3072, acc, wave, lane);         // stale: Whh1
      if (!waitN(fh0 + (t + 1) * 96, 96, abortf, &sres, tid)) return;
      run_seg(ldsW, ldsA, hs0(t + 1), H_, 0, 12, 3072, acc, wave, lane);      // fresh: Wih1
      epi_gates(acc, p.bBenc + tn * 32, nullptr, p.c1, hs1(t + 1), tn, wave, lane);
      __syncthreads();
      if (tid == 0) postf(fh1 + (t + 1) * 96 + tn);
    }
    loadW(ldsW, p.WBdec + (size_t)tn * 98304, 98304, wave, lane);
    for (int t = 0; t < 256; ++t) {
      f32x4 acc[2][2] = {{{0,0,0,0},{0,0,0,0}},{{0,0,0,0},{0,0,0,0}}};
      if (!waitN(fh1 + (256 + t) * 96, 96, abortf, &sres, tid)) return;
      run_seg(ldsW, ldsA, hs1(256 + t), H_, 96, 12, 3072, acc, wave, lane);   // stale: dWhh1
      if (!waitN(fh0 + (257 + t) * 96, 96, abortf, &sres, tid)) return;
      run_seg(ldsW, ldsA, hs0(257 + t), H_, 0, 12, 3072, acc, wave, lane);    // fresh: dWih1
      // ring guard: h1(257+t) overwrites h1(249+t), read by Y when 249+t>=257
      if (t >= 8 && !waitN(yd + (249 + t) * 4, 4, abortf, &sres, tid)) return;
      epi_gates(acc, p.bBdec + tn * 32, nullptr, p.c1, hs1(257 + t), tn, wave, lane);
      __syncthreads();
      if (tid == 0) postf(fh1 + (257 + t) * 96 + tn);
    }
  } else {                                  // ===== role Y: y(256-t) = lin(h1(256+t)) =====
    const int yb = b - 192;
    loadW(ldsW, p.WY + (size_t)yb * 49152, 49152, wave, lane);
    for (int t = 1; t <= 256; ++t) {
      f32x4 acc[2][2] = {{{0,0,0,0},{0,0,0,0}},{{0,0,0,0},{0,0,0,0}}};
      if (!waitN(fh1 + (256 + t) * 96, 96, abortf, &sres, tid)) return;
      run_seg(ldsW, ldsA, hs1(256 + t), H_, 0, 12, 1536, acc, wave, lane);
      if (tid == 0) postf(yd + (256 + t) * 4 + yb);   // reads of h1(256+t) complete
      int tau = 256 - t;
#pragma unroll
      for (int mf = 0; mf < 2; ++mf)
#pragma unroll
        for (int nf = 0; nf < 2; ++nf) {
          int col = nf * 16 + (lane & 15);
          float bia = p.linb[yb * 32 + col];
#pragma unroll
          for (int rg = 0; rg < 4; ++rg) {
            int r = wave * 32 + mf * 16 + ((lane >> 4) << 2) + rg;
            p.out[(long)r * (T_ * F_) + (long)tau * F_ + yb * 32 + col] = acc[mf][nf][rg] + bia;
          }
        }
    }
  }
}

// ---------------- prep kernels (round-3, proven) ----------------
__global__ void k_convx(const float* x, ushort_t* xbf, long n) {
  long st = (long)gridDim.x * 256;
  for (long i = (long)blockIdx.x * 256 + threadIdx.x; i < n; i += st) xbf[i] = f2bf(x[i]);
}

__global__ void k_init(const float* h0in, const float* c0in,
                       ushort_t* h0s0, ushort_t* h1s0, float* c0buf, float* c1buf) {
  int i = blockIdx.x * 256 + threadIdx.x;
  if (i < BH) {
    h0s0[i] = f2bf(h0in[i]);
    h1s0[i] = f2bf(h0in[BH + i]);
    c0buf[i] = c0in[i];
    c1buf[i] = c0in[BH + i];
  }
}

__global__ __launch_bounds__(256) void k_wcomb(const float* A, const float* Bm, float* Cm) {
  __shared__ float sA[16 * 128];
  int tid = threadIdx.x;
  int r0 = blockIdx.x * 16, c0 = blockIdx.y * 128;
  for (int e = tid; e < 16 * 128; e += 256)
    sA[e] = A[(long)(r0 + (e >> 7)) * 128 + (e & 127)];
  __syncthreads();
  int col = c0 + (tid & 127);
  int rg = (tid >> 7) * 8;
  float acc[8] = {0,0,0,0,0,0,0,0};
  for (int k = 0; k < 128; ++k) {
    float bv = Bm[(long)k * 768 + col];
#pragma unroll
    for (int r = 0; r < 8; ++r) acc[r] += sA[(rg + r) * 128 + k] * bv;
  }
  for (int r = 0; r < 8; ++r) Cm[(long)(r0 + rg + r) * 768 + col] = acc[r];
}

__global__ void k_g0(const float* x, const float* dWih0, const float* db0, float* g0p) {
  int i = blockIdx.x * 256 + threadIdx.x;
  if (i >= B_ * NG) return;
  int r = i / NG, n = i % NG;
  int pn = n >> 5, rr = n & 31, g = rr >> 3, u = pn * 8 + (rr & 7);
  int j = g * H_ + u;
  float s = db0[j];
  const float* xr = x + (long)r * (T_ * F_) + (long)(T_ - 1) * F_;
  for (int f = 0; f < 128; ++f) s += xr[f] * dWih0[(long)j * 128 + f];
  g0p[(long)r * NG + n] = s;
}

// pack [s1|s2] (f32) -> per-panel swizzled bf16 LDS image + per-panel bias
__global__ void k_packW(ushort_t* dst, float* bdst, const float* s1, int K1,
                        const float* s2, int K2, const float* bs) {
  int Kt = K1 + K2;
  long total = (long)NG * Kt;
  long st = (long)gridDim.x * 256;
  for (long i = (long)blockIdx.x * 256 + threadIdx.x; i < total; i += st) {
    int n = (int)(i / Kt), k = (int)(i % Kt);
    int pn = n >> 5, rr = n & 31, g = rr >> 3, u = pn * 8 + (rr & 7);
    int j = g * H_ + u;
    float v = (k < K1) ? s1[(long)j * K1 + k] : s2[(long)j * K2 + (k - K1)];
    long byteoff = (long)pn * (64 * (long)Kt) + (long)rr * (2 * Kt)
                 + (long)(((k >> 3) ^ (rr & 7)) << 4) + ((k & 7) << 1);
    dst[byteoff >> 1] = f2bf(v);
    if (k == 0) bdst[pn * 32 + rr] = bs[j];
  }
}

__global__ void k_packY(ushort_t* dst, const float* linW) {
  long total = (long)F_ * H_;
  long st = (long)gridDim.x * 256;
  for (long i = (long)blockIdx.x * 256 + threadIdx.x; i < total; i += st) {
    int f = (int)(i / H_), k = (int)(i % H_);
    int pn = f >> 5, rr = f & 31;
    long byteoff = (long)pn * 49152 + (long)rr * 1536
                 + (long)(((k >> 3) ^ (rr & 7)) << 4) + ((k & 7) << 1);
    dst[byteoff >> 1] = f2bf(linW[(long)f * H_ + k]);
  }
}

// ---------------- host ----------------
extern "C" void kernel_launch(void* const* d_in, const int* in_sizes, int n_in,
                              void* d_out, int out_size, void* d_ws, size_t ws_size,
                              hipStream_t stream)
{
  (void)in_sizes; (void)n_in; (void)out_size; (void)ws_size;
  const float* x     = (const float*)d_in[0];
  const float* h0in  = (const float*)d_in[1];
  const float* c0in  = (const float*)d_in[2];
  const float* eWih0 = (const float*)d_in[3];
  const float* eWhh0 = (const float*)d_in[4];
  const float* eb0   = (const float*)d_in[5];
  const float* eWih1 = (const float*)d_in[6];
  const float* eWhh1 = (const float*)d_in[7];
  const float* eb1   = (const float*)d_in[8];
  const float* dWih0 = (const float*)d_in[9];
  const float* dWhh0 = (const float*)d_in[10];
  const float* db0   = (const float*)d_in[11];
  const float* dWih1 = (const float*)d_in[12];
  const float* dWhh1 = (const float*)d_in[13];
  const float* db1   = (const float*)d_in[14];
  const float* linW  = (const float*)d_in[15];
  const float* linb  = (const float*)d_in[16];
  float* out = (float*)d_out;

  char* wp = (char*)d_ws;
  auto alloc = [&](size_t bytes) -> void* {
    void* pp = (void*)wp;
    wp += (bytes + 255) & ~(size_t)255;
    return pp;
  };
  int* flags = (int*)alloc((size_t)FL_TOTAL * 4);
  ushort_t* xbf   = (ushort_t*)alloc((size_t)B_ * T_ * F_ * 2);
  ushort_t* WAenc = (ushort_t*)alloc((size_t)96 * 57344);
  ushort_t* WBenc = (ushort_t*)alloc((size_t)96 * 98304);
  ushort_t* WAdec = (ushort_t*)alloc((size_t)96 * 98304);
  ushort_t* WBdec = (ushort_t*)alloc((size_t)96 * 98304);
  ushort_t* WY    = (ushort_t*)alloc((size_t)4 * 49152);
  float* Wcomb = (float*)alloc((size_t)NG * H_ * 4);
  float* bAenc = (float*)alloc((size_t)NG * 4);
  float* bBenc = (float*)alloc((size_t)NG * 4);
  float* bAdec = (float*)alloc((size_t)NG * 4);
  float* bBdec = (float*)alloc((size_t)NG * 4);
  float* bcomb = (float*)alloc((size_t)NG * 4);
  float* g0p   = (float*)alloc((size_t)B_ * NG * 4);
  ushort_t* h0ring = (ushort_t*)alloc((size_t)RD * BH * 2);
  ushort_t* h1ring = (ushort_t*)alloc((size_t)RD * BH * 2);
  float* c0buf = (float*)alloc((size_t)BH * 4);
  float* c1buf = (float*)alloc((size_t)BH * 4);

  hipMemsetAsync(flags, 0, (size_t)FL_TOTAL * 4, stream);

  k_convx<<<2048, 256, 0, stream>>>(x, xbf, (long)B_ * T_ * F_);
  k_init<<<(BH + 255) / 256, 256, 0, stream>>>(h0in, c0in, h0ring, h1ring, c0buf, c1buf);
  k_wcomb<<<dim3(192, 6), 256, 0, stream>>>(dWih0, linW, Wcomb);
  k_g0<<<(B_ * NG + 255) / 256, 256, 0, stream>>>(x, dWih0, db0, g0p);
  // bcomb = db0 + dWih0 @ linb, folded into bAdec via k_packW's bias path
  {
    // reuse k_g0-style fold on host-free path: compute bcomb with a tiny kernel
  }
  // bcomb kernel
  {
    struct L { static __global__ void k(const float* dWih0, const float* linb,
                                        const float* db0, float* bc) {
      int j = blockIdx.x * 256 + threadIdx.x;
      if (j < NG) {
        float s = db0[j];
        for (int f = 0; f < 128; ++f) s += dWih0[(long)j * 128 + f] * linb[f];
        bc[j] = s;
      }
    } };
    L::k<<<(NG + 255) / 256, 256, 0, stream>>>(dWih0, linb, db0, bcomb);
  }
  k_packW<<<2048, 256, 0, stream>>>(WAenc, bAenc, eWih0, F_, eWhh0, H_, eb0);
  k_packW<<<2048, 256, 0, stream>>>(WBenc, bBenc, eWih1, H_, eWhh1, H_, eb1);
  k_packW<<<2048, 256, 0, stream>>>(WAdec, bAdec, Wcomb, H_, dWhh0, H_, bcomb);
  k_packW<<<2048, 256, 0, stream>>>(WBdec, bBdec, dWih1, H_, dWhh1, H_, db1);
  k_packY<<<512, 256, 0, stream>>>(WY, linW);

  PR p;
  p.xbf = xbf;
  p.WAenc = (const char*)WAenc; p.WBenc = (const char*)WBenc;
  p.WAdec = (const char*)WAdec; p.WBdec = (const char*)WBdec;
  p.WY = (const char*)WY;
  p.bAenc = bAenc; p.bBenc = bBenc; p.bAdec = bAdec; p.bBdec = bBdec;
  p.g0p = g0p; p.linb = linb;
  p.h0ring = h0ring; p.h1ring = h1ring;
  p.c0 = c0buf; p.c1 = c1buf;
  p.flags = flags;
  p.out = out;

  lstm_res<<<196, 256, 0, stream>>>(p);
}

// Round 6
// 10488.759 us; speedup vs baseline: 1.3351x; 1.3351x over previous
//
#include <hip/hip_runtime.h>

#define B_ 128
#define T_ 256
#define F_ 128
#define H_ 768
#define NG 3072      // 4*H
#define BM 32
#define BN 64
#define BK 128
#define UPT 16       // units per N-tile = BN/4

typedef short s16x8 __attribute__((ext_vector_type(8)));
typedef float f32x4 __attribute__((ext_vector_type(4)));

__device__ __forceinline__ unsigned short f2bf(float x) {
  unsigned u = __float_as_uint(x);
  u += 0x7fffu + ((u >> 16) & 1u);
  return (unsigned short)(u >> 16);
}

__device__ __forceinline__ void async16(const void* g, void* l) {
  __builtin_amdgcn_global_load_lds(
      (const __attribute__((address_space(1))) void*)g,
      (__attribute__((address_space(3))) void*)l, 16, 0, 0);
}

struct Cell {
  const unsigned short* A1; int lda1; int K1;
  const unsigned short* A2; int lda2; int K2;
  const unsigned short* W;  int ldw;
  const float* bias;
  float* c;
  unsigned short* h;
  float* yout; int yt;
  int N; int ngates;
};

__device__ __forceinline__ void compute_frag(const char* At, const char* Bt,
                                             f32x4 acc[2], int wm, int wn, int lane) {
#pragma unroll
  for (int ks = 0; ks < 4; ++ks) {
    int ar = wm*16 + (lane & 15);
    int as = (ks*4 + (lane >> 4)) ^ (ar & 7);
    s16x8 a = *(const s16x8*)(At + ar*256 + as*16);
#pragma unroll
    for (int nf = 0; nf < 2; ++nf) {
      int br = wn*32 + nf*16 + (lane & 15);
      int bsl = (ks*4 + (lane >> 4)) ^ (br & 7);
      s16x8 b = *(const s16x8*)(Bt + br*256 + bsl*16);
      acc[nf] = __builtin_amdgcn_mfma_f32_16x16x32_bf16(a, b, acc[nf], 0, 0, 0);
    }
  }
}

// 192-thread parallel spin: thread i watches fl[i]; one barrier joins. Bounded
// by watchdog + abort flag (bug -> fast visible failure, not a hang).
__device__ bool waitN(int* fl, int count, int* abortf, int* sres, int tid) {
  if (tid == 0) *sres = 1;
  __syncthreads();
  bool ok = true;
  if (tid < count) {
    if (__hip_atomic_load(fl + tid, __ATOMIC_RELAXED, __HIP_MEMORY_SCOPE_AGENT) == 0) {
      int n = 0;
      for (;;) {
        if (__hip_atomic_load(fl + tid, __ATOMIC_RELAXED, __HIP_MEMORY_SCOPE_AGENT) != 0) break;
        __builtin_amdgcn_s_sleep(2);
        if ((++n & 63) == 0) {
          if (__hip_atomic_load(abortf, __ATOMIC_RELAXED, __HIP_MEMORY_SCOPE_AGENT)) { ok = false; break; }
          if (n > 400000) {
            __hip_atomic_store(abortf, 1, __ATOMIC_RELAXED, __HIP_MEMORY_SCOPE_AGENT);
            ok = false; break;
          }
        }
      }
    }
    if (ok) (void)__hip_atomic_load(fl + tid, __ATOMIC_ACQUIRE, __HIP_MEMORY_SCOPE_AGENT);
  }
  if (!ok) *sres = 0;
  __syncthreads();
  return *sres != 0;
}

__device__ __forceinline__ void postf(int* fl) {
  __hip_atomic_store(fl, 1, __ATOMIC_RELEASE, __HIP_MEMORY_SCOPE_AGENT);
}

// ================= encoder kernel: round-4 cell_kernel VERBATIM =================
// modes: 0 = enc dual (384 blk), 2 = generic single (192 blk), 3 = tiny y-final (8)
__global__ __launch_bounds__(256, 2) void enc_kernel(Cell ca, Cell cb, int mode)
{
  __shared__ union SM {
    struct { unsigned short A[3][BM*BK]; unsigned short Bm[3][BN*BK]; } stg; // 72KB
    float gates[BM][BN+4];
  } sm;

  const int bid = (int)blockIdx.x;
  int tm, tn; bool isB = false;
  if (mode == 0) {
    int xcd = bid & 7, j = bid >> 3;          // j 0..47
    isB = j >= 24; int jj = isB ? j - 24 : j;
    tn = xcd * 6 + (jj >> 2); tm = jj & 3;    // 4 tm-blocks of a panel share an XCD
  } else if (mode == 2) {
    int xcd = bid & 7, j = bid >> 3;          // j 0..23
    tn = xcd * 6 + (j >> 2); tm = j & 3;
  } else {
    tm = bid & 3; tn = bid >> 2;
  }
  const Cell C = isB ? cb : ca;
  const int b0 = tm * BM;

  const int tid  = (int)threadIdx.x;
  const int wave = tid >> 6;
  const int lane = tid & 63;
  const int wm = wave >> 1, wn = wave & 1;

  const int nit = (C.K1 + C.K2) / BK;

  f32x4 acc[2] = {{0.f,0.f,0.f,0.f},{0.f,0.f,0.f,0.f}};

  auto stage = [&](int buf, int ck) {
    int kk = ck * BK;
#pragma unroll
    for (int q = 0; q < 2; ++q) {            // A: 8KB
      int cch = wave*2 + q;
      int P = cch*1024 + lane*16;
      int r = P >> 8;
      int sl = ((P >> 4) & 15) ^ (r & 7);
      int ke = kk + sl*8;
      const unsigned short* gp = (ke < C.K1)
        ? (C.A1 + (long)(b0 + r) * C.lda1 + ke)
        : (C.A2 + (long)(b0 + r) * C.lda2 + (ke - C.K1));
      async16(gp, (char*)(sm.stg.A[buf]) + cch*1024);
    }
#pragma unroll
    for (int q = 0; q < 4; ++q) {            // B: 16KB
      int cch = wave*4 + q;
      int P = cch*1024 + lane*16;
      int r = P >> 8;
      int sl = ((P >> 4) & 15) ^ (r & 7);
      int ke = kk + sl*8;
      const unsigned short* gp = C.W + (long)(tn*BN + r) * C.ldw + ke;
      async16(gp, (char*)(sm.stg.Bm[buf]) + cch*1024);
    }
  };

  stage(0, 0);
  stage(1, 1);
  for (int it = 0; it < nit; ++it) {
    if (it + 1 < nit) asm volatile("s_waitcnt vmcnt(6)" ::: "memory");
    else              asm volatile("s_waitcnt vmcnt(0)" ::: "memory");
    __builtin_amdgcn_s_barrier();
    __builtin_amdgcn_sched_barrier(0);
    if (it + 2 < nit) stage((it + 2) % 3, it + 2);
    compute_frag((const char*)sm.stg.A[it % 3], (const char*)sm.stg.Bm[it % 3],
                 acc, wm, wn, lane);
  }

  const int gcol0 = tn * BN;
  if (gcol0 >= C.ngates) {
#pragma unroll
    for (int nf = 0; nf < 2; ++nf) {
      int col = wn*32 + nf*16 + (lane & 15);
      float bia = C.bias[gcol0 + col];
      int fo = gcol0 + col - C.ngates;
#pragma unroll
      for (int rg = 0; rg < 4; ++rg) {
        int brow = wm*16 + (lane >> 4)*4 + rg;
        C.yout[(long)(b0 + brow)*(T_*F_) + (long)C.yt*F_ + fo] = acc[nf][rg] + bia;
      }
    }
    return;
  }

  __syncthreads();
#pragma unroll
  for (int nf = 0; nf < 2; ++nf) {
    int col = wn*32 + nf*16 + (lane & 15);
#pragma unroll
    for (int rg = 0; rg < 4; ++rg) {
      int brow = wm*16 + (lane >> 4)*4 + rg;
      sm.gates[brow][col] = acc[nf][rg];
    }
  }
  __syncthreads();

  const float* bs0 = C.bias + (long)tn*BN;
  for (int e = tid; e < BM*UPT; e += 256) {
    int bl = e >> 4, ul = e & 15;
    float gi = sm.gates[bl][ 0 + ul] + bs0[ 0 + ul];
    float gf = sm.gates[bl][16 + ul] + bs0[16 + ul];
    float gg = sm.gates[bl][32 + ul] + bs0[32 + ul];
    float go = sm.gates[bl][48 + ul] + bs0[48 + ul];
    float iv = 1.f / (1.f + __expf(-gi));
    float fv = 1.f / (1.f + __expf(-gf));
    float gc = fminf(fmaxf(gg, -15.f), 15.f);
    float eg = __expf(2.f * gc);
    float gv = (eg - 1.f) / (eg + 1.f);
    float ov = 1.f / (1.f + __expf(-go));
    long ci = (long)(b0 + bl)*H_ + (long)tn*UPT + ul;
    float c2 = fv * C.c[ci] + iv * gv;
    C.c[ci] = c2;
    float cc = fminf(fmaxf(c2, -15.f), 15.f);
    float ec = __expf(2.f * cc);
    float th = (ec - 1.f) / (ec + 1.f);
    C.h[ci] = f2bf(ov * th);
  }
}

// ======== decoder kernel: merged cd0+cd1, A-panel fully issued up-front ========
// group1 (bid < n0): ca (cd0/cd0ext incl y panels); posts per-block flag after h0 write
// group2 (bid >= n0): cb (cd1); waits all 192 group1 h-flags, then runs.
__global__ __launch_bounds__(256, 1) void dec_kernel(Cell ca, Cell cb, int n0,
                                                     int* fl, int* abortf)
{
  __shared__ union SMD {
    struct { char A[12][8192]; char Bm[3][16384]; } s;   // 96KB + 48KB
    float gates[BM][BN+4];
  } sm;
  __shared__ int sres;

  const int bid = (int)blockIdx.x;
  const int tid = (int)threadIdx.x;
  const int wave = tid >> 6, lane = tid & 63;
  const int wm = wave >> 1, wn = wave & 1;

  const bool isB = bid >= n0;
  int tm, tn;
  if (!isB) {
    int xcd = bid & 7, j = bid >> 3;
    if (j < 24) { tn = xcd*6 + (j >> 2); tm = j & 3; }
    else        { tn = 48 + (xcd >> 2); tm = xcd & 3; }   // y panels (n0==200 only)
  } else {
    int i = bid - n0;
    int xcd = i & 7, j = i >> 3;
    tn = xcd*6 + (j >> 2); tm = j & 3;
  }
  const Cell C = isB ? cb : ca;
  const int b0 = tm * BM;
  const int nit = (C.K1 + C.K2) / BK;        // 7 or 12

  if (isB) { if (!waitN(fl, 192, abortf, &sres, tid)) return; }

  // issue ALL A chunks up-front (h operand: one latency hit, fully parallel)
  for (int c0 = 0; c0 < nit; ++c0) {
    int kk = c0 * BK;
#pragma unroll
    for (int q = 0; q < 2; ++q) {
      int cch = wave*2 + q;
      int P = cch*1024 + lane*16;
      int r = P >> 8;
      int sl = ((P >> 4) & 15) ^ (r & 7);
      int ke = kk + sl*8;
      const unsigned short* gp = (ke < C.K1)
        ? (C.A1 + (long)(b0 + r) * C.lda1 + ke)
        : (C.A2 + (long)(b0 + r) * C.lda2 + (ke - C.K1));
      async16(gp, sm.s.A[c0] + cch*1024);
    }
  }
  auto stageB = [&](int buf, int ck) {
    int kk = ck * BK;
#pragma unroll
    for (int q = 0; q < 4; ++q) {
      int cch = wave*4 + q;
      int P = cch*1024 + lane*16;
      int r = P >> 8;
      int sl = ((P >> 4) & 15) ^ (r & 7);
      int ke = kk + sl*8;
      async16(C.W + (long)(tn*BN + r) * C.ldw + ke, sm.s.Bm[buf] + cch*1024);
    }
  };
  stageB(0, 0);
  stageB(1, 1);

  f32x4 acc[2] = {{0.f,0.f,0.f,0.f},{0.f,0.f,0.f,0.f}};
  // B 3-ring, counted vmcnt(4): one newer B chunk (4 loads/wave) stays in flight.
  // All A loads are older than B0, so any wait also guarantees A completion.
  for (int it = 0; it < nit; ++it) {
    if (it + 1 < nit) asm volatile("s_waitcnt vmcnt(4)" ::: "memory");
    else              asm volatile("s_waitcnt vmcnt(0)" ::: "memory");
    __builtin_amdgcn_s_barrier();
    __builtin_amdgcn_sched_barrier(0);
    if (it + 2 < nit) stageB((it + 2) % 3, it + 2);
    compute_frag(sm.s.A[it], sm.s.Bm[it % 3], acc, wm, wn, lane);
  }

  const int gcol0 = tn * BN;
  if (gcol0 >= C.ngates) {                   // y tile: no flag post
#pragma unroll
    for (int nf = 0; nf < 2; ++nf) {
      int col = wn*32 + nf*16 + (lane & 15);
      float bia = C.bias[gcol0 + col];
      int fo = gcol0 + col - C.ngates;
#pragma unroll
      for (int rg = 0; rg < 4; ++rg) {
        int brow = wm*16 + (lane >> 4)*4 + rg;
        C.yout[(long)(b0 + brow)*(T_*F_) + (long)C.yt*F_ + fo] = acc[nf][rg] + bia;
      }
    }
    return;
  }

  __syncthreads();
#pragma unroll
  for (int nf = 0; nf < 2; ++nf) {
    int col = wn*32 + nf*16 + (lane & 15);
#pragma unroll
    for (int rg = 0; rg < 4; ++rg) {
      int brow = wm*16 + (lane >> 4)*4 + rg;
      sm.gates[brow][col] = acc[nf][rg];
    }
  }
  __syncthreads();

  const float* bs0 = C.bias + (long)tn*BN;
  for (int e = tid; e < BM*UPT; e += 256) {
    int bl = e >> 4, ul = e & 15;
    float gi = sm.gates[bl][ 0 + ul] + bs0[ 0 + ul];
    float gf = sm.gates[bl][16 + ul] + bs0[16 + ul];
    float gg = sm.gates[bl][32 + ul] + bs0[32 + ul];
    float go = sm.gates[bl][48 + ul] + bs0[48 + ul];
    float iv = 1.f / (1.f + __expf(-gi));
    float fv = 1.f / (1.f + __expf(-gf));
    float gc = fminf(fmaxf(gg, -15.f), 15.f);
    float eg = __expf(2.f * gc);
    float gv = (eg - 1.f) / (eg + 1.f);
    float ov = 1.f / (1.f + __expf(-go));
    long ci = (long)(b0 + bl)*H_ + (long)tn*UPT + ul;
    float c2 = fv * C.c[ci] + iv * gv;
    C.c[ci] = c2;
    float cc = fminf(fmaxf(c2, -15.f), 15.f);
    float ec = __expf(2.f * cc);
    float th = (ec - 1.f) / (ec + 1.f);
    C.h[ci] = f2bf(ov * th);
  }
  if (!isB) {
    __syncthreads();                         // all h stores drained (vmcnt0 per wave)
    if (tid == 0) postf(fl + tn*4 + tm);
  }
}

// ---------------- prep kernels (round-4, proven) ----------------
__global__ void k_convx(const float* x, unsigned short* xbf, long n) {
  long st = (long)gridDim.x * 256;
  for (long i = (long)blockIdx.x*256 + threadIdx.x; i < n; i += st) xbf[i] = f2bf(x[i]);
}

__global__ void k_init(const float* h0in, const float* c0in,
                       unsigned short* h0e0, unsigned short* h1e1,
                       float* c0buf, float* c1buf) {
  int i = blockIdx.x*256 + threadIdx.x;
  if (i < B_*H_) {
    h0e0[i] = f2bf(h0in[i]);
    h1e1[i] = f2bf(h0in[B_*H_ + i]);
    c0buf[i] = c0in[i];
    c1buf[i] = c0in[B_*H_ + i];
  }
}

__global__ __launch_bounds__(256) void k_wcomb(const float* A, const float* Bm, float* Cm) {
  __shared__ float sA[16*128];
  int tid = threadIdx.x;
  int r0 = blockIdx.x * 16;
  int c0 = blockIdx.y * 128;
  for (int e = tid; e < 16*128; e += 256)
    sA[e] = A[(long)(r0 + (e >> 7))*128 + (e & 127)];
  __syncthreads();
  int col = c0 + (tid & 127);
  int rg = (tid >> 7) * 8;
  float acc[8] = {0,0,0,0,0,0,0,0};
  for (int k = 0; k < 128; ++k) {
    float b = Bm[(long)k*768 + col];
#pragma unroll
    for (int r = 0; r < 8; ++r) acc[r] += sA[(rg + r)*128 + k] * b;
  }
  for (int r = 0; r < 8; ++r) Cm[(long)(r0 + rg + r)*768 + col] = acc[r];
}

__global__ void k_bcomb(const float* dWih0, const float* linb, const float* db0, float* bc) {
  int j = blockIdx.x*256 + threadIdx.x;
  if (j < NG) {
    float s = db0[j];
    for (int f = 0; f < 128; ++f) s += dWih0[(long)j*128 + f] * linb[f];
    bc[j] = s;
  }
}

__global__ void k_pack(unsigned short* dst, float* bdst, const float* s1, int K1,
                       const float* s2, int K2, const float* bs) {
  long Kt = K1 + K2, total = (long)NG * Kt;
  long st = (long)gridDim.x * 256;
  for (long i = (long)blockIdx.x*256 + threadIdx.x; i < total; i += st) {
    int n = (int)(i / Kt), k = (int)(i % Kt);
    int tn = n >> 6, r = n & 63;
    int j = (r >> 4)*H_ + tn*UPT + (r & 15);
    float v = (k < K1) ? s1[(long)j*K1 + k] : s2[(long)j*K2 + (k - K1)];
    dst[i] = f2bf(v);
    if (k == 0) bdst[n] = bs[j];
  }
}

__global__ void k_packext(unsigned short* dst, float* bdst, const float* wcomb,
                          const float* whh0, const float* bcomb,
                          const float* linW, const float* linb) {
  long total = (long)(NG + F_) * (2*H_);
  long st = (long)gridDim.x * 256;
  for (long i = (long)blockIdx.x*256 + threadIdx.x; i < total; i += st) {
    int n = (int)(i / (2*H_)), k = (int)(i % (2*H_));
    float v;
    if (n < NG) {
      int tn = n >> 6, r = n & 63;
      int j = (r >> 4)*H_ + tn*UPT + (r & 15);
      v = (k < H_) ? wcomb[(long)j*H_ + k] : whh0[(long)j*H_ + (k - H_)];
      if (k == 0) bdst[n] = bcomb[j];
    } else {
      int f = n - NG;
      v = (k < H_) ? linW[(long)f*H_ + k] : 0.f;
      if (k == 0) bdst[n] = linb[f];
    }
    dst[i] = f2bf(v);
  }
}

__global__ void k_packlin(unsigned short* dst, const float* linW) {
  int i = blockIdx.x*256 + threadIdx.x;
  if (i < F_*H_) dst[i] = f2bf(linW[i]);
}

// ---------------- host ----------------
extern "C" void kernel_launch(void* const* d_in, const int* in_sizes, int n_in,
                              void* d_out, int out_size, void* d_ws, size_t ws_size,
                              hipStream_t stream)
{
  (void)in_sizes; (void)n_in; (void)out_size; (void)ws_size;
  const float* x     = (const float*)d_in[0];
  const float* h0in  = (const float*)d_in[1];
  const float* c0in  = (const float*)d_in[2];
  const float* eWih0 = (const float*)d_in[3];
  const float* eWhh0 = (const float*)d_in[4];
  const float* eb0   = (const float*)d_in[5];
  const float* eWih1 = (const float*)d_in[6];
  const float* eWhh1 = (const float*)d_in[7];
  const float* eb1   = (const float*)d_in[8];
  const float* dWih0 = (const float*)d_in[9];
  const float* dWhh0 = (const float*)d_in[10];
  const float* db0   = (const float*)d_in[11];
  const float* dWih1 = (const float*)d_in[12];
  const float* dWhh1 = (const float*)d_in[13];
  const float* db1   = (const float*)d_in[14];
  const float* linW  = (const float*)d_in[15];
  const float* linb  = (const float*)d_in[16];
  float* out = (float*)d_out;

  char* wp = (char*)d_ws;
  auto alloc = [&](size_t bytes) -> void* {
    void* p = (void*)wp;
    wp += (bytes + 255) & ~(size_t)255;
    return p;
  };
  int* flags = (int*)alloc((size_t)(256*192 + 1) * 4);
  int* abortf = flags + 256*192;
  unsigned short* xbf    = (unsigned short*)alloc((size_t)B_*T_*F_*2);
  unsigned short* Wenc0  = (unsigned short*)alloc((size_t)NG*(F_+H_)*2);
  unsigned short* Wenc1  = (unsigned short*)alloc((size_t)NG*(2*H_)*2);
  unsigned short* Wdec0f = (unsigned short*)alloc((size_t)NG*(F_+H_)*2);
  unsigned short* Wext   = (unsigned short*)alloc((size_t)(NG+F_)*(2*H_)*2);
  unsigned short* Wdec1  = (unsigned short*)alloc((size_t)NG*(2*H_)*2);
  unsigned short* linWbf = (unsigned short*)alloc((size_t)F_*H_*2);
  float* Wcomb = (float*)alloc((size_t)NG*H_*4);
  float* benc0 = (float*)alloc((size_t)NG*4);
  float* benc1 = (float*)alloc((size_t)NG*4);
  float* bdec0f= (float*)alloc((size_t)NG*4);
  float* bext  = (float*)alloc((size_t)(NG+F_)*4);
  float* bdec1 = (float*)alloc((size_t)NG*4);
  float* bcomb = (float*)alloc((size_t)NG*4);
  unsigned short* h0e[2];
  h0e[0] = (unsigned short*)alloc((size_t)B_*H_*2);
  h0e[1] = (unsigned short*)alloc((size_t)B_*H_*2);
  unsigned short* h1e[2];
  h1e[0] = (unsigned short*)alloc((size_t)B_*H_*2);
  h1e[1] = (unsigned short*)alloc((size_t)B_*H_*2);
  float* c0buf = (float*)alloc((size_t)B_*H_*4);
  float* c1buf = (float*)alloc((size_t)B_*H_*4);

  hipMemsetAsync(flags, 0, (size_t)(256*192 + 1) * 4, stream);

  // ---- prep
  k_convx<<<2048, 256, 0, stream>>>(x, xbf, (long)B_*T_*F_);
  k_init<<<(B_*H_+255)/256, 256, 0, stream>>>(h0in, c0in, h0e[0], h1e[1], c0buf, c1buf);
  k_wcomb<<<dim3(192,6), 256, 0, stream>>>(dWih0, linW, Wcomb);
  k_bcomb<<<(NG+255)/256, 256, 0, stream>>>(dWih0, linb, db0, bcomb);
  k_pack<<<2048, 256, 0, stream>>>(Wenc0, benc0, eWih0, F_, eWhh0, H_, eb0);
  k_pack<<<2048, 256, 0, stream>>>(Wenc1, benc1, eWih1, H_, eWhh1, H_, eb1);
  k_pack<<<2048, 256, 0, stream>>>(Wdec0f, bdec0f, dWih0, F_, dWhh0, H_, db0);
  k_pack<<<2048, 256, 0, stream>>>(Wdec1, bdec1, dWih1, H_, dWhh1, H_, db1);
  k_packext<<<2048, 256, 0, stream>>>(Wext, bext, Wcomb, dWhh0, bcomb, linW, linb);
  k_packlin<<<(F_*H_+255)/256, 256, 0, stream>>>(linWbf, linW);

  auto mk = [&](const unsigned short* A1, int lda1, int K1,
                const unsigned short* A2, int lda2, int K2,
                const unsigned short* W, const float* bias,
                float* c, unsigned short* h, float* yo, int yt,
                int N, int ngates) {
    Cell cc; cc.A1=A1; cc.lda1=lda1; cc.K1=K1; cc.A2=A2; cc.lda2=lda2; cc.K2=K2;
    cc.W=W; cc.ldw=K1+K2; cc.bias=bias; cc.c=c; cc.h=h; cc.yout=yo; cc.yt=yt;
    cc.N=N; cc.ngates=ngates;
    return cc;
  };

  // ---- encoder: stage s runs enc-layer0(t=s) and enc-layer1(t=s-1) (round-4)
  for (int s = 0; s <= T_; ++s) {
    Cell cA = {}, cB = {};
    bool hasA = (s < T_), hasB = (s >= 1);
    if (hasA)
      cA = mk(xbf + (long)s*F_, T_*F_, F_, h0e[s&1], H_, H_,
              Wenc0, benc0, c0buf, h0e[(s+1)&1], nullptr, 0, NG, NG);
    if (hasB)
      cB = mk(h0e[s&1], H_, H_, h1e[s&1], H_, H_,
              Wenc1, benc1, c1buf, h1e[(s+1)&1], nullptr, 0, NG, NG);
    if (hasA && hasB) enc_kernel<<<384, 256, 0, stream>>>(cA, cB, 0);
    else if (hasA)    enc_kernel<<<192, 256, 0, stream>>>(cA, cA, 2);
    else              enc_kernel<<<192, 256, 0, stream>>>(cB, cB, 2);
  }

  // ---- decoder: merged cd0(t)+cd1(t) per launch, intra-launch flag handshake
  {
    // t=0: cd0(0) = [x_last | h0_fin] @ Wdec0f, then cd1(0)
    Cell c0f = mk(xbf + (long)(T_-1)*F_, T_*F_, F_, h0e[0], H_, H_,
                  Wdec0f, bdec0f, c0buf, h0e[1], nullptr, 0, NG, NG);
    Cell c10 = mk(h0e[1], H_, H_, h1e[1], H_, H_,
                  Wdec1, bdec1, c1buf, h1e[0], nullptr, 0, NG, NG);
    dec_kernel<<<384, 256, 0, stream>>>(c0f, c10, 192, flags + 0, abortf);
  }
  for (int t = 1; t < T_; ++t) {
    Cell cd0 = mk(h1e[(t+1)&1], H_, H_, h0e[t&1], H_, H_,
                  Wext, bext, c0buf, h0e[(t+1)&1], out, T_-t, NG+F_, NG);
    Cell cd1 = mk(h0e[(t+1)&1], H_, H_, h1e[(t+1)&1], H_, H_,
                  Wdec1, bdec1, c1buf, h1e[t&1], nullptr, 0, NG, NG);
    dec_kernel<<<392, 256, 0, stream>>>(cd0, cd1, 200, flags + (long)t*192, abortf);
  }
  {
    // final y(T-1) -> out[:,0,:]
    Cell cy = mk(h1e[1], H_, H_, h1e[1], H_, 0,
                 linWbf, linb, nullptr, nullptr, out, 0, F_, 0);
    enc_kernel<<<8, 256, 0, stream>>>(cy, cy, 3);
  }
}

// Round 7
// 7053.712 us; speedup vs baseline: 1.9852x; 1.4870x over previous
//
#include <hip/hip_runtime.h>

#define B_ 128
#define T_ 256
#define F_ 128
#define H_ 768
#define NG 3072      // 4*H
#define BM 32
#define BN 64
#define BK 128
#define UPT 16       // units per N-tile = BN/4

typedef short s16x8 __attribute__((ext_vector_type(8)));
typedef float f32x4 __attribute__((ext_vector_type(4)));

__device__ __forceinline__ unsigned short f2bf(float x) {
  unsigned u = __float_as_uint(x);
  u += 0x7fffu + ((u >> 16) & 1u);
  return (unsigned short)(u >> 16);
}

__device__ __forceinline__ void async16(const void* g, void* l) {
  __builtin_amdgcn_global_load_lds(
      (const __attribute__((address_space(1))) void*)g,
      (__attribute__((address_space(3))) void*)l, 16, 0, 0);
}

struct Cell {
  const unsigned short* A1; int lda1; int K1;
  const unsigned short* A2; int lda2; int K2;
  const unsigned short* W;  int ldw;
  const float* bias;
  float* c;
  unsigned short* h;
  float* yout; int yt;
  int N; int ngates;
};

__device__ __forceinline__ void compute_frag(const char* At, const char* Bt,
                                             f32x4 acc[2], int wm, int wn, int lane) {
#pragma unroll
  for (int ks = 0; ks < 4; ++ks) {
    int ar = wm*16 + (lane & 15);
    int as = (ks*4 + (lane >> 4)) ^ (ar & 7);
    s16x8 a = *(const s16x8*)(At + ar*256 + as*16);
#pragma unroll
    for (int nf = 0; nf < 2; ++nf) {
      int br = wn*32 + nf*16 + (lane & 15);
      int bsl = (ks*4 + (lane >> 4)) ^ (br & 7);
      s16x8 b = *(const s16x8*)(Bt + br*256 + bsl*16);
      acc[nf] = __builtin_amdgcn_mfma_f32_16x16x32_bf16(a, b, acc[nf], 0, 0, 0);
    }
  }
}

// ================= encoder kernel: round-4 cell_kernel VERBATIM =================
// modes: 0 = enc dual (384 blk), 2 = generic single (192 blk), 3 = tiny y-final (8)
__global__ __launch_bounds__(256, 2) void enc_kernel(Cell ca, Cell cb, int mode)
{
  __shared__ union SM {
    struct { unsigned short A[3][BM*BK]; unsigned short Bm[3][BN*BK]; } stg; // 72KB
    float gates[BM][BN+4];
  } sm;

  const int bid = (int)blockIdx.x;
  int tm, tn; bool isB = false;
  if (mode == 0) {
    int xcd = bid & 7, j = bid >> 3;          // j 0..47
    isB = j >= 24; int jj = isB ? j - 24 : j;
    tn = xcd * 6 + (jj >> 2); tm = jj & 3;    // 4 tm-blocks of a panel share an XCD
  } else if (mode == 2) {
    int xcd = bid & 7, j = bid >> 3;          // j 0..23
    tn = xcd * 6 + (j >> 2); tm = j & 3;
  } else {
    tm = bid & 3; tn = bid >> 2;
  }
  const Cell C = isB ? cb : ca;
  const int b0 = tm * BM;

  const int tid  = (int)threadIdx.x;
  const int wave = tid >> 6;
  const int lane = tid & 63;
  const int wm = wave >> 1, wn = wave & 1;

  const int nit = (C.K1 + C.K2) / BK;

  f32x4 acc[2] = {{0.f,0.f,0.f,0.f},{0.f,0.f,0.f,0.f}};

  auto stage = [&](int buf, int ck) {
    int kk = ck * BK;
#pragma unroll
    for (int q = 0; q < 2; ++q) {            // A: 8KB
      int cch = wave*2 + q;
      int P = cch*1024 + lane*16;
      int r = P >> 8;
      int sl = ((P >> 4) & 15) ^ (r & 7);
      int ke = kk + sl*8;
      const unsigned short* gp = (ke < C.K1)
        ? (C.A1 + (long)(b0 + r) * C.lda1 + ke)
        : (C.A2 + (long)(b0 + r) * C.lda2 + (ke - C.K1));
      async16(gp, (char*)(sm.stg.A[buf]) + cch*1024);
    }
#pragma unroll
    for (int q = 0; q < 4; ++q) {            // B: 16KB
      int cch = wave*4 + q;
      int P = cch*1024 + lane*16;
      int r = P >> 8;
      int sl = ((P >> 4) & 15) ^ (r & 7);
      int ke = kk + sl*8;
      const unsigned short* gp = C.W + (long)(tn*BN + r) * C.ldw + ke;
      async16(gp, (char*)(sm.stg.Bm[buf]) + cch*1024);
    }
  };

  stage(0, 0);
  stage(1, 1);
  for (int it = 0; it < nit; ++it) {
    if (it + 1 < nit) asm volatile("s_waitcnt vmcnt(6)" ::: "memory");
    else              asm volatile("s_waitcnt vmcnt(0)" ::: "memory");
    __builtin_amdgcn_s_barrier();
    __builtin_amdgcn_sched_barrier(0);
    if (it + 2 < nit) stage((it + 2) % 3, it + 2);
    compute_frag((const char*)sm.stg.A[it % 3], (const char*)sm.stg.Bm[it % 3],
                 acc, wm, wn, lane);
  }

  const int gcol0 = tn * BN;
  if (gcol0 >= C.ngates) {
#pragma unroll
    for (int nf = 0; nf < 2; ++nf) {
      int col = wn*32 + nf*16 + (lane & 15);
      float bia = C.bias[gcol0 + col];
      int fo = gcol0 + col - C.ngates;
#pragma unroll
      for (int rg = 0; rg < 4; ++rg) {
        int brow = wm*16 + (lane >> 4)*4 + rg;
        C.yout[(long)(b0 + brow)*(T_*F_) + (long)C.yt*F_ + fo] = acc[nf][rg] + bia;
      }
    }
    return;
  }

  __syncthreads();
#pragma unroll
  for (int nf = 0; nf < 2; ++nf) {
    int col = wn*32 + nf*16 + (lane & 15);
#pragma unroll
    for (int rg = 0; rg < 4; ++rg) {
      int brow = wm*16 + (lane >> 4)*4 + rg;
      sm.gates[brow][col] = acc[nf][rg];
    }
  }
  __syncthreads();

  const float* bs0 = C.bias + (long)tn*BN;
  for (int e = tid; e < BM*UPT; e += 256) {
    int bl = e >> 4, ul = e & 15;
    float gi = sm.gates[bl][ 0 + ul] + bs0[ 0 + ul];
    float gf = sm.gates[bl][16 + ul] + bs0[16 + ul];
    float gg = sm.gates[bl][32 + ul] + bs0[32 + ul];
    float go = sm.gates[bl][48 + ul] + bs0[48 + ul];
    float iv = 1.f / (1.f + __expf(-gi));
    float fv = 1.f / (1.f + __expf(-gf));
    float gc = fminf(fmaxf(gg, -15.f), 15.f);
    float eg = __expf(2.f * gc);
    float gv = (eg - 1.f) / (eg + 1.f);
    float ov = 1.f / (1.f + __expf(-go));
    long ci = (long)(b0 + bl)*H_ + (long)tn*UPT + ul;
    float c2 = fv * C.c[ci] + iv * gv;
    C.c[ci] = c2;
    float cc = fminf(fmaxf(c2, -15.f), 15.f);
    float ec = __expf(2.f * cc);
    float th = (ec - 1.f) / (ec + 1.f);
    C.h[ci] = f2bf(ov * th);
  }
}

// ======== decoder kernel: single cell, FULL-A up-front + B 3-ring + c prefetch ========
// modes: 1 = cd0ext (200 blk, j==24 -> y panels tn 48/49), 2 = generic (192 blk)
__global__ __launch_bounds__(256, 1) void dec_kernel(Cell C, int mode)
{
  __shared__ struct SMD {
    char A[12][8192];        // 96KB: whole A panel, one chunk per K=128 slab
    char Bm[3][16384];       // 48KB: B ring
    float ctile[BM][UPT];    // 2KB: prefetched c state
    float gates[BM][BN+4];   // 8.5KB
  } sm;                      // ~155KB -> 1 block/CU

  const int bid = (int)blockIdx.x;
  const int tid = (int)threadIdx.x;
  const int wave = tid >> 6, lane = tid & 63;
  const int wm = wave >> 1, wn = wave & 1;

  int tm, tn;
  if (mode == 1) {
    int xcd = bid & 7, j = bid >> 3;
    if (j < 24) { tn = xcd*6 + (j >> 2); tm = j & 3; }
    else        { tn = 48 + (xcd >> 2); tm = xcd & 3; }   // y panels
  } else {
    int xcd = bid & 7, j = bid >> 3;
    tn = xcd*6 + (j >> 2); tm = j & 3;
  }
  const int b0 = tm * BM;
  const int nit = (C.K1 + C.K2) / BK;        // 7 or 12
  const int gcol0 = tn * BN;
  const bool hasC = (C.c != nullptr) && (gcol0 < C.ngates);

  // ---- prefetch c tile (32x16 f32, 2KB): each wave issues exactly 1 load (halves duplicated)
  if (hasC) {
    int off = (wave & 1) * 1024 + lane * 16;  // byte offset into ctile
    int r = off >> 6, cc = (off & 63) >> 2;   // 64B per row of 16 floats
    async16(C.c + (long)(b0 + r) * H_ + (long)tn * UPT + cc,
            &sm.ctile[r][cc]);
  }

  // ---- issue the ENTIRE A panel up-front: 2 loads/wave per chunk, fully parallel
  for (int ck = 0; ck < nit; ++ck) {
    int kk = ck * BK;
#pragma unroll
    for (int q = 0; q < 2; ++q) {
      int cch = wave*2 + q;
      int P = cch*1024 + lane*16;
      int r = P >> 8;
      int sl = ((P >> 4) & 15) ^ (r & 7);
      int ke = kk + sl*8;
      const unsigned short* gp = (ke < C.K1)
        ? (C.A1 + (long)(b0 + r) * C.lda1 + ke)
        : (C.A2 + (long)(b0 + r) * C.lda2 + (ke - C.K1));
      async16(gp, sm.A[ck] + cch*1024);
    }
  }

  auto stageB = [&](int buf, int ck) {
    int kk = ck * BK;
#pragma unroll
    for (int q = 0; q < 4; ++q) {
      int cch = wave*4 + q;
      int P = cch*1024 + lane*16;
      int r = P >> 8;
      int sl = ((P >> 4) & 15) ^ (r & 7);
      int ke = kk + sl*8;
      async16(C.W + (long)(tn*BN + r) * C.ldw + ke, sm.Bm[buf] + cch*1024);
    }
  };
  stageB(0, 0);
  if (nit > 1) stageB(1, 1);

  f32x4 acc[2] = {{0.f,0.f,0.f,0.f},{0.f,0.f,0.f,0.f}};
  // B ring with counted vmcnt(4): B_{it+1} (4 loads/wave) may stay in flight; all
  // A loads + c are older than B_{it}, so each wait also guarantees their completion.
  for (int it = 0; it < nit; ++it) {
    if (it + 1 < nit) asm volatile("s_waitcnt vmcnt(4)" ::: "memory");
    else              asm volatile("s_waitcnt vmcnt(0)" ::: "memory");
    __builtin_amdgcn_s_barrier();
    __builtin_amdgcn_sched_barrier(0);
    if (it + 2 < nit) stageB((it + 2) % 3, it + 2);
    compute_frag(sm.A[it], sm.Bm[it % 3], acc, wm, wn, lane);
  }

  if (gcol0 >= C.ngates) {                   // y tile: write straight to output
#pragma unroll
    for (int nf = 0; nf < 2; ++nf) {
      int col = wn*32 + nf*16 + (lane & 15);
      float bia = C.bias[gcol0 + col];
      int fo = gcol0 + col - C.ngates;
#pragma unroll
      for (int rg = 0; rg < 4; ++rg) {
        int brow = wm*16 + (lane >> 4)*4 + rg;
        C.yout[(long)(b0 + brow)*(T_*F_) + (long)C.yt*F_ + fo] = acc[nf][rg] + bia;
      }
    }
    return;
  }

  __syncthreads();
#pragma unroll
  for (int nf = 0; nf < 2; ++nf) {
    int col = wn*32 + nf*16 + (lane & 15);
#pragma unroll
    for (int rg = 0; rg < 4; ++rg) {
      int brow = wm*16 + (lane >> 4)*4 + rg;
      sm.gates[brow][col] = acc[nf][rg];
    }
  }
  __syncthreads();

  const float* bs0 = C.bias + (long)tn*BN;
  for (int e = tid; e < BM*UPT; e += 256) {
    int bl = e >> 4, ul = e & 15;
    float gi = sm.gates[bl][ 0 + ul] + bs0[ 0 + ul];
    float gf = sm.gates[bl][16 + ul] + bs0[16 + ul];
    float gg = sm.gates[bl][32 + ul] + bs0[32 + ul];
    float go = sm.gates[bl][48 + ul] + bs0[48 + ul];
    float iv = 1.f / (1.f + __expf(-gi));
    float fv = 1.f / (1.f + __expf(-gf));
    float gc = fminf(fmaxf(gg, -15.f), 15.f);
    float eg = __expf(2.f * gc);
    float gv = (eg - 1.f) / (eg + 1.f);
    float ov = 1.f / (1.f + __expf(-go));
    long ci = (long)(b0 + bl)*H_ + (long)tn*UPT + ul;
    float c2 = fv * sm.ctile[bl][ul] + iv * gv;   // c from LDS (prefetched)
    C.c[ci] = c2;
    float cc = fminf(fmaxf(c2, -15.f), 15.f);
    float ec = __expf(2.f * cc);
    float th = (ec - 1.f) / (ec + 1.f);
    C.h[ci] = f2bf(ov * th);
  }
}

// ---------------- prep kernels (round-4, proven) ----------------
__global__ void k_convx(const float* x, unsigned short* xbf, long n) {
  long st = (long)gridDim.x * 256;
  for (long i = (long)blockIdx.x*256 + threadIdx.x; i < n; i += st) xbf[i] = f2bf(x[i]);
}

__global__ void k_init(const float* h0in, const float* c0in,
                       unsigned short* h0e0, unsigned short* h1e1,
                       float* c0buf, float* c1buf) {
  int i = blockIdx.x*256 + threadIdx.x;
  if (i < B_*H_) {
    h0e0[i] = f2bf(h0in[i]);
    h1e1[i] = f2bf(h0in[B_*H_ + i]);
    c0buf[i] = c0in[i];
    c1buf[i] = c0in[B_*H_ + i];
  }
}

__global__ __launch_bounds__(256) void k_wcomb(const float* A, const float* Bm, float* Cm) {
  __shared__ float sA[16*128];
  int tid = threadIdx.x;
  int r0 = blockIdx.x * 16;
  int c0 = blockIdx.y * 128;
  for (int e = tid; e < 16*128; e += 256)
    sA[e] = A[(long)(r0 + (e >> 7))*128 + (e & 127)];
  __syncthreads();
  int col = c0 + (tid & 127);
  int rg = (tid >> 7) * 8;
  float acc[8] = {0,0,0,0,0,0,0,0};
  for (int k = 0; k < 128; ++k) {
    float b = Bm[(long)k*768 + col];
#pragma unroll
    for (int r = 0; r < 8; ++r) acc[r] += sA[(rg + r)*128 + k] * b;
  }
  for (int r = 0; r < 8; ++r) Cm[(long)(r0 + rg + r)*768 + col] = acc[r];
}

__global__ void k_bcomb(const float* dWih0, const float* linb, const float* db0, float* bc) {
  int j = blockIdx.x*256 + threadIdx.x;
  if (j < NG) {
    float s = db0[j];
    for (int f = 0; f < 128; ++f) s += dWih0[(long)j*128 + f] * linb[f];
    bc[j] = s;
  }
}

__global__ void k_pack(unsigned short* dst, float* bdst, const float* s1, int K1,
                       const float* s2, int K2, const float* bs) {
  long Kt = K1 + K2, total = (long)NG * Kt;
  long st = (long)gridDim.x * 256;
  for (long i = (long)blockIdx.x*256 + threadIdx.x; i < total; i += st) {
    int n = (int)(i / Kt), k = (int)(i % Kt);
    int tn = n >> 6, r = n & 63;
    int j = (r >> 4)*H_ + tn*UPT + (r & 15);
    float v = (k < K1) ? s1[(long)j*K1 + k] : s2[(long)j*K2 + (k - K1)];
    dst[i] = f2bf(v);
    if (k == 0) bdst[n] = bs[j];
  }
}

__global__ void k_packext(unsigned short* dst, float* bdst, const float* wcomb,
                          const float* whh0, const float* bcomb,
                          const float* linW, const float* linb) {
  long total = (long)(NG + F_) * (2*H_);
  long st = (long)gridDim.x * 256;
  for (long i = (long)blockIdx.x*256 + threadIdx.x; i < total; i += st) {
    int n = (int)(i / (2*H_)), k = (int)(i % (2*H_));
    float v;
    if (n < NG) {
      int tn = n >> 6, r = n & 63;
      int j = (r >> 4)*H_ + tn*UPT + (r & 15);
      v = (k < H_) ? wcomb[(long)j*H_ + k] : whh0[(long)j*H_ + (k - H_)];
      if (k == 0) bdst[n] = bcomb[j];
    } else {
      int f = n - NG;
      v = (k < H_) ? linW[(long)f*H_ + k] : 0.f;
      if (k == 0) bdst[n] = linb[f];
    }
    dst[i] = f2bf(v);
  }
}

__global__ void k_packlin(unsigned short* dst, const float* linW) {
  int i = blockIdx.x*256 + threadIdx.x;
  if (i < F_*H_) dst[i] = f2bf(linW[i]);
}

// ---------------- host ----------------
extern "C" void kernel_launch(void* const* d_in, const int* in_sizes, int n_in,
                              void* d_out, int out_size, void* d_ws, size_t ws_size,
                              hipStream_t stream)
{
  (void)in_sizes; (void)n_in; (void)out_size; (void)ws_size;
  const float* x     = (const float*)d_in[0];
  const float* h0in  = (const float*)d_in[1];
  const float* c0in  = (const float*)d_in[2];
  const float* eWih0 = (const float*)d_in[3];
  const float* eWhh0 = (const float*)d_in[4];
  const float* eb0   = (const float*)d_in[5];
  const float* eWih1 = (const float*)d_in[6];
  const float* eWhh1 = (const float*)d_in[7];
  const float* eb1   = (const float*)d_in[8];
  const float* dWih0 = (const float*)d_in[9];
  const float* dWhh0 = (const float*)d_in[10];
  const float* db0   = (const float*)d_in[11];
  const float* dWih1 = (const float*)d_in[12];
  const float* dWhh1 = (const float*)d_in[13];
  const float* db1   = (const float*)d_in[14];
  const float* linW  = (const float*)d_in[15];
  const float* linb  = (const float*)d_in[16];
  float* out = (float*)d_out;

  char* wp = (char*)d_ws;
  auto alloc = [&](size_t bytes) -> void* {
    void* p = (void*)wp;
    wp += (bytes + 255) & ~(size_t)255;
    return p;
  };
  unsigned short* xbf    = (unsigned short*)alloc((size_t)B_*T_*F_*2);
  unsigned short* Wenc0  = (unsigned short*)alloc((size_t)NG*(F_+H_)*2);
  unsigned short* Wenc1  = (unsigned short*)alloc((size_t)NG*(2*H_)*2);
  unsigned short* Wdec0f = (unsigned short*)alloc((size_t)NG*(F_+H_)*2);
  unsigned short* Wext   = (unsigned short*)alloc((size_t)(NG+F_)*(2*H_)*2);
  unsigned short* Wdec1  = (unsigned short*)alloc((size_t)NG*(2*H_)*2);
  unsigned short* linWbf = (unsigned short*)alloc((size_t)F_*H_*2);
  float* Wcomb = (float*)alloc((size_t)NG*H_*4);
  float* benc0 = (float*)alloc((size_t)NG*4);
  float* benc1 = (float*)alloc((size_t)NG*4);
  float* bdec0f= (float*)alloc((size_t)NG*4);
  float* bext  = (float*)alloc((size_t)(NG+F_)*4);
  float* bdec1 = (float*)alloc((size_t)NG*4);
  float* bcomb = (float*)alloc((size_t)NG*4);
  unsigned short* h0e[2];
  h0e[0] = (unsigned short*)alloc((size_t)B_*H_*2);
  h0e[1] = (unsigned short*)alloc((size_t)B_*H_*2);
  unsigned short* h1e[2];
  h1e[0] = (unsigned short*)alloc((size_t)B_*H_*2);
  h1e[1] = (unsigned short*)alloc((size_t)B_*H_*2);
  float* c0buf = (float*)alloc((size_t)B_*H_*4);
  float* c1buf = (float*)alloc((size_t)B_*H_*4);

  // ---- prep
  k_convx<<<2048, 256, 0, stream>>>(x, xbf, (long)B_*T_*F_);
  k_init<<<(B_*H_+255)/256, 256, 0, stream>>>(h0in, c0in, h0e[0], h1e[1], c0buf, c1buf);
  k_wcomb<<<dim3(192,6), 256, 0, stream>>>(dWih0, linW, Wcomb);
  k_bcomb<<<(NG+255)/256, 256, 0, stream>>>(dWih0, linb, db0, bcomb);
  k_pack<<<2048, 256, 0, stream>>>(Wenc0, benc0, eWih0, F_, eWhh0, H_, eb0);
  k_pack<<<2048, 256, 0, stream>>>(Wenc1, benc1, eWih1, H_, eWhh1, H_, eb1);
  k_pack<<<2048, 256, 0, stream>>>(Wdec0f, bdec0f, dWih0, F_, dWhh0, H_, db0);
  k_pack<<<2048, 256, 0, stream>>>(Wdec1, bdec1, dWih1, H_, dWhh1, H_, db1);
  k_packext<<<2048, 256, 0, stream>>>(Wext, bext, Wcomb, dWhh0, bcomb, linW, linb);
  k_packlin<<<(F_*H_+255)/256, 256, 0, stream>>>(linWbf, linW);

  auto mk = [&](const unsigned short* A1, int lda1, int K1,
                const unsigned short* A2, int lda2, int K2,
                const unsigned short* W, const float* bias,
                float* c, unsigned short* h, float* yo, int yt,
                int N, int ngates) {
    Cell cc; cc.A1=A1; cc.lda1=lda1; cc.K1=K1; cc.A2=A2; cc.lda2=lda2; cc.K2=K2;
    cc.W=W; cc.ldw=K1+K2; cc.bias=bias; cc.c=c; cc.h=h; cc.yout=yo; cc.yt=yt;
    cc.N=N; cc.ngates=ngates;
    return cc;
  };

  // ---- encoder: stage s runs enc-layer0(t=s) and enc-layer1(t=s-1) (round-4 verbatim)
  for (int s = 0; s <= T_; ++s) {
    Cell cA = {}, cB = {};
    bool hasA = (s < T_), hasB = (s >= 1);
    if (hasA)
      cA = mk(xbf + (long)s*F_, T_*F_, F_, h0e[s&1], H_, H_,
              Wenc0, benc0, c0buf, h0e[(s+1)&1], nullptr, 0, NG, NG);
    if (hasB)
      cB = mk(h0e[s&1], H_, H_, h1e[s&1], H_, H_,
              Wenc1, benc1, c1buf, h1e[(s+1)&1], nullptr, 0, NG, NG);
    if (hasA && hasB) enc_kernel<<<384, 256, 0, stream>>>(cA, cB, 0);
    else if (hasA)    enc_kernel<<<192, 256, 0, stream>>>(cA, cA, 2);
    else              enc_kernel<<<192, 256, 0, stream>>>(cB, cB, 2);
  }

  // ---- decoder: two launches per t with the new full-A dec_kernel
  {
    Cell c0f = mk(xbf + (long)(T_-1)*F_, T_*F_, F_, h0e[0], H_, H_,
                  Wdec0f, bdec0f, c0buf, h0e[1], nullptr, 0, NG, NG);
    dec_kernel<<<192, 256, 0, stream>>>(c0f, 2);
    Cell c10 = mk(h0e[1], H_, H_, h1e[1], H_, H_,
                  Wdec1, bdec1, c1buf, h1e[0], nullptr, 0, NG, NG);
    dec_kernel<<<192, 256, 0, stream>>>(c10, 2);
  }
  for (int t = 1; t < T_; ++t) {
    Cell cd0 = mk(h1e[(t+1)&1], H_, H_, h0e[t&1], H_, H_,
                  Wext, bext, c0buf, h0e[(t+1)&1], out, T_-t, NG+F_, NG);
    dec_kernel<<<200, 256, 0, stream>>>(cd0, 1);
    Cell cd1 = mk(h0e[(t+1)&1], H_, H_, h1e[(t+1)&1], H_, H_,
                  Wdec1, bdec1, c1buf, h1e[t&1], nullptr, 0, NG, NG);
    dec_kernel<<<192, 256, 0, stream>>>(cd1, 2);
  }
  {
    Cell cy = mk(h1e[1], H_, H_, h1e[1], H_, 0,
                 linWbf, linb, nullptr, nullptr, out, 0, F_, 0);
    enc_kernel<<<8, 256, 0, stream>>>(cy, cy, 3);
  }
}